// Round 2
// baseline (7526.542 us; speedup 1.0000x reference)
//
#include <hip/hip_runtime.h>

// LSTM_76622216560744: 2-layer LSTM (H=50), B=2048, T=1024, input dim 1.
// R2 design: block=128 threads (2 waves), BS=4 batches/block, grid=512
// (2 blocks/CU). Each lane owns TWO gate rows (tid, tid+128) so one
// ds_read_b128 of h feeds 8 FMAs (was 4) -> LDS-pipe traffic per batch
// halves. Weights in per-lane registers (~304 floats, 1 wave/SIMD).

#define TT 1024
#define HH 50
#define GG 200      // 4*H gate rows
#define BS 4        // batch per block
#define NT 128      // threads per block (2 waves)
#define HROW 104    // h12s row stride: h1[0:50] h2[50:100], padded
#define GPAD 256    // gs row stride (rows 200..255 are dummy-row sink)

__device__ __forceinline__ float fast_rcp(float x) { return __builtin_amdgcn_rcpf(x); }
__device__ __forceinline__ float sigm(float x) { return fast_rcp(1.0f + __expf(-x)); }
__device__ __forceinline__ float ftanh(float x) {
    float e = __expf(-2.0f * x);
    return (1.0f - e) * fast_rcp(1.0f + e);
}

__global__ __launch_bounds__(NT, 1) void lstm_kernel(
    const float* __restrict__ x,
    const float* __restrict__ W_ih1, const float* __restrict__ W_hh1,
    const float* __restrict__ b_ih1, const float* __restrict__ b_hh1,
    const float* __restrict__ W_ih2, const float* __restrict__ W_hh2,
    const float* __restrict__ b_ih2, const float* __restrict__ b_hh2,
    const float* __restrict__ W_lin, const float* __restrict__ b_lin,
    float* __restrict__ out)
{
    __shared__ float xs[BS * TT];        // 16 KB staged input
    __shared__ float h12s[BS * HROW];    // [h1|h2] per batch
    __shared__ float gs[BS * GPAD];      // gate exchange

    const int tid = threadIdx.x;
    const int b0g = blockIdx.x * BS;

    // Stage x (coalesced float4 copy of 4 contiguous rows).
    {
        const float4* xg = (const float4*)(x + (size_t)b0g * TT);
        float4* xs4 = (float4*)xs;
        for (int i = tid; i < BS * TT / 4; i += NT) xs4[i] = xg[i];
    }
    for (int i = tid; i < BS * HROW; i += NT) h12s[i] = 0.0f;

    // Two gate rows per lane: r0 = tid, r1 = tid+128 (>=200 -> zero weights).
    const int r0 = tid;
    const int r1 = tid + NT;
    const float v1 = (r1 < GG) ? 1.0f : 0.0f;
    const int r1c = (r1 < GG) ? r1 : 0;

    float w1a[52], w1b[52], w2a[100], w2b[100];
    const float wx0 = W_ih1[r0];
    const float wx1 = v1 * W_ih1[r1c];
    const float b10 = b_ih1[r0] + b_hh1[r0];
    const float b11 = v1 * (b_ih1[r1c] + b_hh1[r1c]);
    const float b20 = b_ih2[r0] + b_hh2[r0];
    const float b21 = v1 * (b_ih2[r1c] + b_hh2[r1c]);
    #pragma unroll
    for (int k = 0; k < HH; ++k) {
        w1a[k] = W_hh1[r0 * HH + k];
        w1b[k] = v1 * W_hh1[r1c * HH + k];
    }
    w1a[50] = w1a[51] = w1b[50] = w1b[51] = 0.0f;
    #pragma unroll
    for (int k = 0; k < HH; ++k) {
        w2a[k]      = W_ih2[r0 * HH + k];
        w2b[k]      = v1 * W_ih2[r1c * HH + k];
        w2a[50 + k] = W_hh2[r0 * HH + k];
        w2b[50 + k] = v1 * W_hh2[r1c * HH + k];
    }

    // Cell-update mapping: u = tid&63 (<50 active), bq = tid>>6;
    // thread updates unit u for batches bq and bq+2.
    const int u = tid & 63;
    const int bq = tid >> 6;
    const bool upd = (u < HH);
    float c1[2] = {0.f, 0.f}, c2[2] = {0.f, 0.f};

    __syncthreads();

    for (int t = 0; t < TT; ++t) {
        float a0[BS], a1[BS];
        // ---- Layer 1 gates: wx*x_t + bias + Whh1 @ h1 (k padded to 52) ----
        #pragma unroll
        for (int b = 0; b < BS; ++b) {
            float xv = xs[b * TT + t];
            a0[b] = b10 + wx0 * xv;
            a1[b] = b11 + wx1 * xv;
        }
        #pragma unroll
        for (int kc = 0; kc < 52; kc += 4) {
            #pragma unroll
            for (int b = 0; b < BS; ++b) {
                float4 h4 = *(const float4*)&h12s[b * HROW + kc];
                a0[b] += w1a[kc] * h4.x + w1a[kc + 1] * h4.y
                       + w1a[kc + 2] * h4.z + w1a[kc + 3] * h4.w;
                a1[b] += w1b[kc] * h4.x + w1b[kc + 1] * h4.y
                       + w1b[kc + 2] * h4.z + w1b[kc + 3] * h4.w;
            }
        }
        #pragma unroll
        for (int b = 0; b < BS; ++b) {
            gs[b * GPAD + r0] = a0[b];
            gs[b * GPAD + r1] = a1[b];
        }
        __syncthreads();

        // ---- Layer 1 cell/hidden update ----
        if (upd) {
            #pragma unroll
            for (int j = 0; j < 2; ++j) {
                int b = bq + 2 * j;
                float gi = gs[b * GPAD + u];
                float gf = gs[b * GPAD + u + 50];
                float gc = gs[b * GPAD + u + 100];
                float go = gs[b * GPAD + u + 150];
                float cn = sigm(gf) * c1[j] + sigm(gi) * ftanh(gc);
                c1[j] = cn;
                h12s[b * HROW + u] = sigm(go) * ftanh(cn);
            }
        }
        __syncthreads();

        // ---- Layer 2 gates: bias + [Wih2|Whh2] @ [h1;h2] (k=100) ----
        #pragma unroll
        for (int b = 0; b < BS; ++b) { a0[b] = b20; a1[b] = b21; }
        #pragma unroll
        for (int kc = 0; kc < 100; kc += 4) {
            #pragma unroll
            for (int b = 0; b < BS; ++b) {
                float4 h4 = *(const float4*)&h12s[b * HROW + kc];
                a0[b] += w2a[kc] * h4.x + w2a[kc + 1] * h4.y
                       + w2a[kc + 2] * h4.z + w2a[kc + 3] * h4.w;
                a1[b] += w2b[kc] * h4.x + w2b[kc + 1] * h4.y
                       + w2b[kc + 2] * h4.z + w2b[kc + 3] * h4.w;
            }
        }
        #pragma unroll
        for (int b = 0; b < BS; ++b) {
            gs[b * GPAD + r0] = a0[b];
            gs[b * GPAD + r1] = a1[b];
        }
        __syncthreads();

        // ---- Layer 2 cell/hidden update ----
        if (upd) {
            #pragma unroll
            for (int j = 0; j < 2; ++j) {
                int b = bq + 2 * j;
                float gi = gs[b * GPAD + u];
                float gf = gs[b * GPAD + u + 50];
                float gc = gs[b * GPAD + u + 100];
                float go = gs[b * GPAD + u + 150];
                float cn = sigm(gf) * c2[j] + sigm(gi) * ftanh(gc);
                c2[j] = cn;
                h12s[b * HROW + 50 + u] = sigm(go) * ftanh(cn);
            }
        }
        __syncthreads();
    }

    // Final linear: out[b] = W_lin . h2_final + b_lin
    if (tid < BS) {
        float s = b_lin[0];
        #pragma unroll
        for (int k = 0; k < HH; ++k) s += W_lin[k] * h12s[tid * HROW + 50 + k];
        out[b0g + tid] = s;
    }
}

extern "C" void kernel_launch(void* const* d_in, const int* in_sizes, int n_in,
                              void* d_out, int out_size, void* d_ws, size_t ws_size,
                              hipStream_t stream) {
    const float* x     = (const float*)d_in[0];
    const float* W_ih1 = (const float*)d_in[1];
    const float* W_hh1 = (const float*)d_in[2];
    const float* b_ih1 = (const float*)d_in[3];
    const float* b_hh1 = (const float*)d_in[4];
    const float* W_ih2 = (const float*)d_in[5];
    const float* W_hh2 = (const float*)d_in[6];
    const float* b_ih2 = (const float*)d_in[7];
    const float* b_hh2 = (const float*)d_in[8];
    const float* W_lin = (const float*)d_in[9];
    const float* b_lin = (const float*)d_in[10];
    float* out = (float*)d_out;

    const int Btot = in_sizes[0] / TT;   // 2048
    const int nblocks = Btot / BS;       // 512 -> 2 blocks/CU

    lstm_kernel<<<nblocks, NT, 0, stream>>>(
        x, W_ih1, W_hh1, b_ih1, b_hh1, W_ih2, W_hh2, b_ih2, b_hh2,
        W_lin, b_lin, out);
}

// Round 3
// 2297.868 us; speedup vs baseline: 3.2754x; 3.2754x over previous
//
#include <hip/hip_runtime.h>

// LSTM_76622216560744: 2-layer LSTM (H=50), B=2048, T=1024, input dim 1.
// R3: split-bf16 MFMA (16x16x32). M = 200 gate rows reordered row'=unit*4+type,
// N = 16 (8 real batches), K = [x,h1] (L1) / [h1,h2] (L2). Weights live as
// A-frags in registers (hi/lo bf16 split, 3-product scheme). Gates exit MFMA
// with (i,f,g,o) of one (unit,batch) in one lane's 4 C-regs -> in-register
// cell update, c-state in VGPRs. Layer 2 skewed one step -> 2 barriers/step.

#define TT 1024
#define HH 50
#define NB 8     // real batches per block
#define NT 256   // 4 waves
#define NP 4     // max M-tile pairs per wave (13 tiles over 4 waves)

typedef __bf16 bf16x8 __attribute__((ext_vector_type(8)));
typedef unsigned short ushort8 __attribute__((ext_vector_type(8)));
typedef float f32x4 __attribute__((ext_vector_type(4)));

__device__ __forceinline__ unsigned short bf16_rne(float f) {
    unsigned u = __float_as_uint(f);
    return (unsigned short)((u + 0x7fffu + ((u >> 16) & 1u)) >> 16);
}
__device__ __forceinline__ float bf16_tof(unsigned short h) {
    return __uint_as_float((unsigned)h << 16);
}
__device__ __forceinline__ float fast_rcp(float x) { return __builtin_amdgcn_rcpf(x); }
__device__ __forceinline__ float sigm(float x) { return fast_rcp(1.0f + __expf(-x)); }
__device__ __forceinline__ float ftanh(float x) {
    float e = __expf(-2.0f * x);
    return (1.0f - e) * fast_rcp(1.0f + e);
}

// element index into v-buffers (frag-ready blocked layout): k-block c=k>>3 of
// 16 batches x 8 k's:  idx = (k>>3)*128 + n*8 + (k&7)
__device__ __forceinline__ int vidx(int k, int n) {
    return ((k >> 3) << 7) + n * 8 + (k & 7);
}

__global__ __launch_bounds__(NT, 1) void lstm_kernel(
    const float* __restrict__ x,
    const float* __restrict__ W_ih1, const float* __restrict__ W_hh1,
    const float* __restrict__ b_ih1, const float* __restrict__ b_hh1,
    const float* __restrict__ W_ih2, const float* __restrict__ W_hh2,
    const float* __restrict__ b_ih2, const float* __restrict__ b_hh2,
    const float* __restrict__ W_lin, const float* __restrict__ b_lin,
    float* __restrict__ out)
{
    __shared__ float xs[TT * NB];  // x transposed [t][b], 32 KB
    __shared__ __attribute__((aligned(16))) unsigned short v1h[1024], v1l[1024]; // [64k][16n]
    __shared__ __attribute__((aligned(16))) unsigned short v2h[2048], v2l[2048]; // [128k][16n]

    const int tid  = threadIdx.x;
    const int w    = tid >> 6;
    const int L    = tid & 63;
    const int quad = L >> 4;
    const int n15  = L & 15;
    const int b0g  = blockIdx.x * NB;

    for (int i = tid; i < 1024; i += NT) { v1h[i] = 0; v1l[i] = 0; }
    for (int i = tid; i < 2048; i += NT) { v2h[i] = 0; v2l[i] = 0; }
    // stage x transposed: global read coalesced (i = b*1024 + t)
    for (int i = tid; i < NB * TT; i += NT) {
        int b = i >> 10, t = i & 1023;
        xs[t * NB + b] = x[(size_t)b0g * TT + i];
    }

    // ---- per-wave M-tile pairs: tiles m = w + 4p, m < 13 ----
    const int np = (16 - w) >> 2;   // w=0 -> 4 tiles, else 3
    bf16x8 a1h[NP][2], a1l[NP][2], a2h[NP][4], a2l[NP][4];
    f32x4 bias1[NP], bias2[NP];
    float c1[NP], c2[NP];

    #pragma unroll
    for (int p = 0; p < NP; ++p) {
        c1[p] = 0.f; c2[p] = 0.f;
        const int m = w + 4 * p;
        const bool pv = (p < np);
        // A-frag row this lane holds: arow = m*16 + (L&15)
        const int arow = m * 16 + n15;
        const bool av = pv && (arow < 200);
        const int r = av ? ((arow & 3) * 50 + (arow >> 2)) : 0; // orig row: type*50+unit
        #pragma unroll
        for (int kt = 0; kt < 2; ++kt) {   // L1: K = [x, h1, pad] (64)
            ushort8 th, tl;
            #pragma unroll
            for (int j = 0; j < 8; ++j) {
                int k = kt * 32 + quad * 8 + j;
                float wv = 0.f;
                if (av) { if (k == 0) wv = W_ih1[r]; else if (k <= 50) wv = W_hh1[r * 50 + k - 1]; }
                unsigned short hh = bf16_rne(wv);
                th[j] = hh; tl[j] = bf16_rne(wv - bf16_tof(hh));
            }
            a1h[p][kt] = __builtin_bit_cast(bf16x8, th);
            a1l[p][kt] = __builtin_bit_cast(bf16x8, tl);
        }
        #pragma unroll
        for (int kt = 0; kt < 4; ++kt) {   // L2: K = [h1, h2, pad] (128)
            ushort8 th, tl;
            #pragma unroll
            for (int j = 0; j < 8; ++j) {
                int k = kt * 32 + quad * 8 + j;
                float wv = 0.f;
                if (av) { if (k < 50) wv = W_ih2[r * 50 + k]; else if (k < 100) wv = W_hh2[r * 50 + k - 50]; }
                unsigned short hh = bf16_rne(wv);
                th[j] = hh; tl[j] = bf16_rne(wv - bf16_tof(hh));
            }
            a2h[p][kt] = __builtin_bit_cast(bf16x8, th);
            a2l[p][kt] = __builtin_bit_cast(bf16x8, tl);
        }
        f32x4 bb1, bb2;
        #pragma unroll
        for (int reg = 0; reg < 4; ++reg) { // C rows this lane holds
            int crow = m * 16 + quad * 4 + reg;
            float v1b = 0.f, v2b = 0.f;
            if (pv && crow < 200) {
                int rr = (crow & 3) * 50 + (crow >> 2);
                v1b = b_ih1[rr] + b_hh1[rr];
                v2b = b_ih2[rr] + b_hh2[rr];
            }
            bb1[reg] = v1b; bb2[reg] = v2b;
        }
        bias1[p] = bb1; bias2[p] = bb2;
    }

    __syncthreads();
    if (tid < NB) {                     // write x_0 into v1 (k=0)
        float xv = xs[0 * NB + tid];
        unsigned short hh = bf16_rne(xv);
        v1h[vidx(0, tid)] = hh;
        v1l[vidx(0, tid)] = bf16_rne(xv - bf16_tof(hh));
    }
    __syncthreads();

    // ---- main loop: iteration t computes L1 gates(t) and L2 gates(t-1) ----
    for (int t = 0; t <= TT; ++t) {
        // phase 1: B-frag loads (conflict-free, lane-linear 16B)
        bf16x8 b1h[2], b1l[2], b2h[4], b2l[4];
        #pragma unroll
        for (int kt = 0; kt < 2; ++kt) {
            b1h[kt] = ((const bf16x8*)v1h)[kt * 64 + L];
            b1l[kt] = ((const bf16x8*)v1l)[kt * 64 + L];
        }
        #pragma unroll
        for (int kt = 0; kt < 4; ++kt) {
            b2h[kt] = ((const bf16x8*)v2h)[kt * 64 + L];
            b2l[kt] = ((const bf16x8*)v2l)[kt * 64 + L];
        }

        f32x4 acc1[NP], acc2[NP];
        if (t < TT) {
            #pragma unroll
            for (int p = 0; p < NP; ++p) if (p < np) {
                f32x4 a = bias1[p];
                #pragma unroll
                for (int kt = 0; kt < 2; ++kt) {
                    a = __builtin_amdgcn_mfma_f32_16x16x32_bf16(a1h[p][kt], b1h[kt], a, 0, 0, 0);
                    a = __builtin_amdgcn_mfma_f32_16x16x32_bf16(a1h[p][kt], b1l[kt], a, 0, 0, 0);
                    a = __builtin_amdgcn_mfma_f32_16x16x32_bf16(a1l[p][kt], b1h[kt], a, 0, 0, 0);
                }
                acc1[p] = a;
            }
        }
        if (t > 0) {
            #pragma unroll
            for (int p = 0; p < NP; ++p) if (p < np) {
                f32x4 a = bias2[p];
                #pragma unroll
                for (int kt = 0; kt < 4; ++kt) {
                    a = __builtin_amdgcn_mfma_f32_16x16x32_bf16(a2h[p][kt], b2h[kt], a, 0, 0, 0);
                    a = __builtin_amdgcn_mfma_f32_16x16x32_bf16(a2h[p][kt], b2l[kt], a, 0, 0, 0);
                    a = __builtin_amdgcn_mfma_f32_16x16x32_bf16(a2l[p][kt], b2h[kt], a, 0, 0, 0);
                }
                acc2[p] = a;
            }
        }
        __syncthreads();   // reads done before this step's h writes

        // phase 2: in-register cell updates, write split-bf16 h
        if (t < TT) {
            #pragma unroll
            for (int p = 0; p < NP; ++p) {
                const int u = (w + 4 * p) * 4 + quad;
                if (p < np && u < HH) {
                    float cn = sigm(acc1[p][1]) * c1[p] + sigm(acc1[p][0]) * ftanh(acc1[p][2]);
                    c1[p] = cn;
                    float h = sigm(acc1[p][3]) * ftanh(cn);
                    if (n15 < NB) {
                        unsigned short hh = bf16_rne(h);
                        unsigned short hl = bf16_rne(h - bf16_tof(hh));
                        v1h[vidx(1 + u, n15)] = hh; v1l[vidx(1 + u, n15)] = hl;
                        v2h[vidx(u, n15)]     = hh; v2l[vidx(u, n15)]     = hl;
                    }
                }
            }
        }
        if (t > 0) {
            #pragma unroll
            for (int p = 0; p < NP; ++p) {
                const int u = (w + 4 * p) * 4 + quad;
                if (p < np && u < HH) {
                    float cn = sigm(acc2[p][1]) * c2[p] + sigm(acc2[p][0]) * ftanh(acc2[p][2]);
                    c2[p] = cn;
                    float h = sigm(acc2[p][3]) * ftanh(cn);
                    if (n15 < NB) {
                        unsigned short hh = bf16_rne(h);
                        unsigned short hl = bf16_rne(h - bf16_tof(hh));
                        v2h[vidx(50 + u, n15)] = hh; v2l[vidx(50 + u, n15)] = hl;
                    }
                }
            }
        }
        if (tid < NB && t + 1 < TT) {   // x for next iteration
            float xv = xs[(t + 1) * NB + tid];
            unsigned short hh = bf16_rne(xv);
            v1h[vidx(0, tid)] = hh;
            v1l[vidx(0, tid)] = bf16_rne(xv - bf16_tof(hh));
        }
        __syncthreads();   // writes visible to next iteration's reads
    }

    // epilogue: out[b] = W_lin . h2(T-1) + b_lin  (h2 final sits in v2[50..99])
    if (tid < NB) {
        float s = b_lin[0];
        #pragma unroll
        for (int u = 0; u < HH; ++u) {
            int id = vidx(50 + u, tid);
            s += W_lin[u] * (bf16_tof(v2h[id]) + bf16_tof(v2l[id]));
        }
        out[b0g + tid] = s;
    }
}

extern "C" void kernel_launch(void* const* d_in, const int* in_sizes, int n_in,
                              void* d_out, int out_size, void* d_ws, size_t ws_size,
                              hipStream_t stream) {
    const float* x     = (const float*)d_in[0];
    const float* W_ih1 = (const float*)d_in[1];
    const float* W_hh1 = (const float*)d_in[2];
    const float* b_ih1 = (const float*)d_in[3];
    const float* b_hh1 = (const float*)d_in[4];
    const float* W_ih2 = (const float*)d_in[5];
    const float* W_hh2 = (const float*)d_in[6];
    const float* b_ih2 = (const float*)d_in[7];
    const float* b_hh2 = (const float*)d_in[8];
    const float* W_lin = (const float*)d_in[9];
    const float* b_lin = (const float*)d_in[10];
    float* out = (float*)d_out;

    const int Btot = in_sizes[0] / TT;   // 2048
    const int nblocks = Btot / NB;       // 256 -> 1 block/CU

    lstm_kernel<<<nblocks, NT, 0, stream>>>(
        x, W_ih1, W_hh1, b_ih1, b_hh1, W_ih2, W_hh2, b_ih2, b_hh2,
        W_lin, b_lin, out);
}

// Round 4
// 1341.880 us; speedup vs baseline: 5.6090x; 1.7124x over previous
//
#include <hip/hip_runtime.h>

// LSTM_76622216560744: 2-layer LSTM (H=50), B=2048, T=1024, input dim 1.
// R4: split-bf16 MFMA (16x16x32), M=200 gate rows (row'=unit*4+type), N=16
// (8 real batches), combined K=128 B-operand [x | h1 | h2 | pad] shared by
// both layers (L1 uses kt0-1, L2 kt0-3). 8 waves/block (2/SIMD) for latency
// hiding; exec-masked B-loads (n<8) halve DS volume; double-buffered v ->
// ONE barrier per step. Weights as split-bf16 A-frags in registers; c-state
// and cell update fully in-lane (C/D layout: 4 regs = i,f,g,o of one unit).

#define TT 1024
#define HH 50
#define NB 8     // real batches per block
#define NT 512   // 8 waves, 2 per SIMD
#define NTILE 13 // ceil(200/16) M-tiles

typedef __bf16 bf16x8 __attribute__((ext_vector_type(8)));
typedef unsigned short ushort8 __attribute__((ext_vector_type(8)));
typedef float f32x4 __attribute__((ext_vector_type(4)));

__device__ __forceinline__ unsigned short bf16_rne(float f) {
    unsigned u = __float_as_uint(f);
    return (unsigned short)((u + 0x7fffu + ((u >> 16) & 1u)) >> 16);
}
__device__ __forceinline__ float bf16_tof(unsigned short h) {
    return __uint_as_float((unsigned)h << 16);
}
__device__ __forceinline__ float fast_rcp(float x) { return __builtin_amdgcn_rcpf(x); }
__device__ __forceinline__ float sigm(float x) { return fast_rcp(1.0f + __expf(-x)); }
__device__ __forceinline__ float ftanh(float x) {
    float e = __expf(-2.0f * x);
    return (1.0f - e) * fast_rcp(1.0f + e);
}

// frag-ready blocked layout: idx = (k>>3)*128 + n*8 + (k&7), k<128, n<16
__device__ __forceinline__ int vidx(int k, int n) {
    return ((k >> 3) << 7) + n * 8 + (k & 7);
}

__global__ __launch_bounds__(NT, 2) void lstm_kernel(
    const float* __restrict__ x,
    const float* __restrict__ W_ih1, const float* __restrict__ W_hh1,
    const float* __restrict__ b_ih1, const float* __restrict__ b_hh1,
    const float* __restrict__ W_ih2, const float* __restrict__ W_hh2,
    const float* __restrict__ b_ih2, const float* __restrict__ b_hh2,
    const float* __restrict__ W_lin, const float* __restrict__ b_lin,
    float* __restrict__ out)
{
    __shared__ float xs[TT * NB];                                      // 32 KB
    __shared__ __attribute__((aligned(16))) unsigned short vh[2][2048]; // 8 KB
    __shared__ __attribute__((aligned(16))) unsigned short vl[2][2048]; // 8 KB

    const int tid  = threadIdx.x;
    const int w    = tid >> 6;       // wave 0..7
    const int L    = tid & 63;
    const int quad = L >> 4;
    const int n15  = L & 15;
    const int b0g  = blockIdx.x * NB;

    for (int i = tid; i < 2 * 2048; i += NT) { ((unsigned short*)vh)[i] = 0; ((unsigned short*)vl)[i] = 0; }
    // stage x transposed: xs[t][b]; global read coalesced (i = b*1024 + t)
    for (int i = tid; i < NB * TT; i += NT) {
        int b = i >> 10, t = i & 1023;
        xs[t * NB + b] = x[(size_t)b0g * TT + i];
    }

    // ---- per-wave M-tiles: m = w and m = w+8 (if < 13) ----
    const bool p1v = (w + 8) < NTILE;
    bf16x8 a1h[2][2], a1l[2][2], a2h[2][4], a2l[2][4];
    f32x4 bias1[2], bias2[2];
    float c1[2] = {0.f, 0.f}, c2[2] = {0.f, 0.f};

    #pragma unroll
    for (int p = 0; p < 2; ++p) {
        const int m = w + 8 * p;
        const bool pv = (p == 0) || p1v;
        const int arow = m * 16 + n15;
        const bool av = pv && (arow < 200);
        const int r = av ? ((arow & 3) * 50 + (arow >> 2)) : 0; // type*50+unit
        // L1 A: k=0 -> W_ih1, k in [1,50] -> W_hh1 col k-1 (kt0-1 only)
        #pragma unroll
        for (int kt = 0; kt < 2; ++kt) {
            ushort8 th, tl;
            #pragma unroll
            for (int j = 0; j < 8; ++j) {
                int k = kt * 32 + quad * 8 + j;
                float wv = 0.f;
                if (av) { if (k == 0) wv = W_ih1[r]; else if (k <= 50) wv = W_hh1[r * 50 + k - 1]; }
                unsigned short hh = bf16_rne(wv);
                th[j] = hh; tl[j] = bf16_rne(wv - bf16_tof(hh));
            }
            a1h[p][kt] = __builtin_bit_cast(bf16x8, th);
            a1l[p][kt] = __builtin_bit_cast(bf16x8, tl);
        }
        // L2 A: k in [1,50] -> W_ih2 col k-1 (h1), k in [51,100] -> W_hh2 col k-51
        #pragma unroll
        for (int kt = 0; kt < 4; ++kt) {
            ushort8 th, tl;
            #pragma unroll
            for (int j = 0; j < 8; ++j) {
                int k = kt * 32 + quad * 8 + j;
                float wv = 0.f;
                if (av) {
                    if (k >= 1 && k <= 50) wv = W_ih2[r * 50 + k - 1];
                    else if (k >= 51 && k <= 100) wv = W_hh2[r * 50 + k - 51];
                }
                unsigned short hh = bf16_rne(wv);
                th[j] = hh; tl[j] = bf16_rne(wv - bf16_tof(hh));
            }
            a2h[p][kt] = __builtin_bit_cast(bf16x8, th);
            a2l[p][kt] = __builtin_bit_cast(bf16x8, tl);
        }
        f32x4 bb1, bb2;
        #pragma unroll
        for (int reg = 0; reg < 4; ++reg) {
            int crow = m * 16 + quad * 4 + reg;
            float v1b = 0.f, v2b = 0.f;
            if (pv && crow < 200) {
                int rr = (crow & 3) * 50 + (crow >> 2);
                v1b = b_ih1[rr] + b_hh1[rr];
                v2b = b_ih2[rr] + b_hh2[rr];
            }
            bb1[reg] = v1b; bb2[reg] = v2b;
        }
        bias1[p] = bb1; bias2[p] = bb2;
    }

    __syncthreads();
    if (tid < NB) {                      // x(0) into buf0, slot k=0
        float xv = xs[0 * NB + tid];
        unsigned short hh = bf16_rne(xv);
        vh[0][vidx(0, tid)] = hh;
        vl[0][vidx(0, tid)] = bf16_rne(xv - bf16_tof(hh));
    }
    __syncthreads();

    // B-frag regs: lanes n>=8 stay zero forever (exec-masked loads)
    bf16x8 bh[4], bl[4];
    #pragma unroll
    for (int kt = 0; kt < 4; ++kt) {
        bh[kt] = __builtin_bit_cast(bf16x8, ushort8{0,0,0,0,0,0,0,0});
        bl[kt] = __builtin_bit_cast(bf16x8, ushort8{0,0,0,0,0,0,0,0});
    }

    // ---- main loop: iter t = L1 gates(t) + L2 gates(t-1); 1 barrier/step ----
    for (int t = 0; t <= TT; ++t) {
        const int rb = t & 1, wb = rb ^ 1;
        const unsigned short* vhr = vh[rb];
        const unsigned short* vlr = vl[rb];
        unsigned short* vhw = vh[wb];
        unsigned short* vlw = vl[wb];

        if (n15 < NB) {
            #pragma unroll
            for (int kt = 0; kt < 4; ++kt) {
                bh[kt] = ((const bf16x8*)vhr)[kt * 64 + L];
                bl[kt] = ((const bf16x8*)vlr)[kt * 64 + L];
            }
        }

        f32x4 acc1[2], acc2[2];
        if (t < TT) {
            #pragma unroll
            for (int p = 0; p < 2; ++p) if (p == 0 || p1v) {
                f32x4 a = bias1[p];
                #pragma unroll
                for (int kt = 0; kt < 2; ++kt) {
                    a = __builtin_amdgcn_mfma_f32_16x16x32_bf16(a1h[p][kt], bh[kt], a, 0, 0, 0);
                    a = __builtin_amdgcn_mfma_f32_16x16x32_bf16(a1h[p][kt], bl[kt], a, 0, 0, 0);
                    a = __builtin_amdgcn_mfma_f32_16x16x32_bf16(a1l[p][kt], bh[kt], a, 0, 0, 0);
                }
                acc1[p] = a;
            }
        }
        if (t > 0) {
            #pragma unroll
            for (int p = 0; p < 2; ++p) if (p == 0 || p1v) {
                f32x4 a = bias2[p];
                #pragma unroll
                for (int kt = 0; kt < 4; ++kt) {
                    a = __builtin_amdgcn_mfma_f32_16x16x32_bf16(a2h[p][kt], bh[kt], a, 0, 0, 0);
                    a = __builtin_amdgcn_mfma_f32_16x16x32_bf16(a2h[p][kt], bl[kt], a, 0, 0, 0);
                    a = __builtin_amdgcn_mfma_f32_16x16x32_bf16(a2l[p][kt], bh[kt], a, 0, 0, 0);
                }
                acc2[p] = a;
            }
        }

        // cell updates (in-lane; reg = gate type i,f,g,o), write h to wbuf
        if (t < TT) {
            #pragma unroll
            for (int p = 0; p < 2; ++p) if (p == 0 || p1v) {
                const int u = (w + 8 * p) * 4 + quad;
                if (u < HH && n15 < NB) {
                    float cn = sigm(acc1[p][1]) * c1[p] + sigm(acc1[p][0]) * ftanh(acc1[p][2]);
                    c1[p] = cn;
                    float h = sigm(acc1[p][3]) * ftanh(cn);
                    unsigned short hh = bf16_rne(h);
                    unsigned short hl = bf16_rne(h - bf16_tof(hh));
                    vhw[vidx(1 + u, n15)] = hh;
                    vlw[vidx(1 + u, n15)] = hl;
                }
            }
        }
        if (t > 0) {
            #pragma unroll
            for (int p = 0; p < 2; ++p) if (p == 0 || p1v) {
                const int u = (w + 8 * p) * 4 + quad;
                if (u < HH && n15 < NB) {
                    float cn = sigm(acc2[p][1]) * c2[p] + sigm(acc2[p][0]) * ftanh(acc2[p][2]);
                    c2[p] = cn;
                    float h = sigm(acc2[p][3]) * ftanh(cn);
                    unsigned short hh = bf16_rne(h);
                    unsigned short hl = bf16_rne(h - bf16_tof(hh));
                    vhw[vidx(51 + u, n15)] = hh;
                    vlw[vidx(51 + u, n15)] = hl;
                }
            }
        }
        if (tid < NB && t + 1 < TT) {    // x(t+1) into wbuf slot 0
            float xv = xs[(t + 1) * NB + tid];
            unsigned short hh = bf16_rne(xv);
            vhw[vidx(0, tid)] = hh;
            vlw[vidx(0, tid)] = bf16_rne(xv - bf16_tof(hh));
        }
        __syncthreads();   // orders writes(t) before reads(t+1); reads(t) are
                           // in regs pre-barrier; writes(t+1) hit the other buf
    }

    // epilogue: h2(T-1) sits in buf[(TT+1)&1] = buf1, slots 51..100
    if (tid < NB) {
        float s = b_lin[0];
        #pragma unroll
        for (int u = 0; u < HH; ++u) {
            int id = vidx(51 + u, tid);
            s += W_lin[u] * (bf16_tof(vh[1][id]) + bf16_tof(vl[1][id]));
        }
        out[b0g + tid] = s;
    }
}

extern "C" void kernel_launch(void* const* d_in, const int* in_sizes, int n_in,
                              void* d_out, int out_size, void* d_ws, size_t ws_size,
                              hipStream_t stream) {
    const float* x     = (const float*)d_in[0];
    const float* W_ih1 = (const float*)d_in[1];
    const float* W_hh1 = (const float*)d_in[2];
    const float* b_ih1 = (const float*)d_in[3];
    const float* b_hh1 = (const float*)d_in[4];
    const float* W_ih2 = (const float*)d_in[5];
    const float* W_hh2 = (const float*)d_in[6];
    const float* b_ih2 = (const float*)d_in[7];
    const float* b_hh2 = (const float*)d_in[8];
    const float* W_lin = (const float*)d_in[9];
    const float* b_lin = (const float*)d_in[10];
    float* out = (float*)d_out;

    const int Btot = in_sizes[0] / TT;   // 2048
    const int nblocks = Btot / NB;       // 256 -> 1 block/CU

    lstm_kernel<<<nblocks, NT, 0, stream>>>(
        x, W_ih1, W_hh1, b_ih1, b_hh1, W_ih2, W_hh2, b_ih2, b_hh2,
        W_lin, b_lin, out);
}

// Round 5
// 1137.450 us; speedup vs baseline: 6.6170x; 1.1797x over previous
//
#include <hip/hip_runtime.h>

// LSTM_76622216560744: 2-layer LSTM (H=50), B=2048, T=1024, input dim 1.
// R5: split-bf16 MFMA (16x16x32), M=200 gate rows (row'=unit*4+type), N=16
// (8 real batches), combined K=128 B-operand [x | h1 | h2 | pad]. 16 waves
// per block (4/SIMD forced co-residency -> VGPR<=128) with ONE M-tile per
// wave (waves 0..12 work, 13..15 stage x). Double-buffered v, 1 barrier per
// step, 2x-unrolled t-loop with literal buffer pointers. Weights as split
// bf16 A-frags in registers; cell update fully in-lane; c-state in VGPRs.

#define TT 1024
#define HH 50
#define NB 8     // real batches per block
#define NT 1024  // 16 waves, 4 per SIMD
#define NTILE 13 // ceil(200/16) M-tiles

typedef __bf16 bf16x8 __attribute__((ext_vector_type(8)));
typedef unsigned short ushort8 __attribute__((ext_vector_type(8)));
typedef float f32x4 __attribute__((ext_vector_type(4)));

__device__ __forceinline__ unsigned short bf16_rne(float f) {
    unsigned u = __float_as_uint(f);
    return (unsigned short)((u + 0x7fffu + ((u >> 16) & 1u)) >> 16);
}
__device__ __forceinline__ float bf16_tof(unsigned short h) {
    return __uint_as_float((unsigned)h << 16);
}
__device__ __forceinline__ float fast_rcp(float x) { return __builtin_amdgcn_rcpf(x); }
__device__ __forceinline__ float sigm(float x) { return fast_rcp(1.0f + __expf(-x)); }
__device__ __forceinline__ float ftanh(float x) {
    float e = __expf(-2.0f * x);
    return (1.0f - e) * fast_rcp(1.0f + e);
}

// frag-ready blocked layout: idx = (k>>3)*128 + n*8 + (k&7), k<128, n<16
__device__ __forceinline__ int vidx(int k, int n) {
    return ((k >> 3) << 7) + n * 8 + (k & 7);
}

__global__ __launch_bounds__(NT) void lstm_kernel(
    const float* __restrict__ x,
    const float* __restrict__ W_ih1, const float* __restrict__ W_hh1,
    const float* __restrict__ b_ih1, const float* __restrict__ b_hh1,
    const float* __restrict__ W_ih2, const float* __restrict__ W_hh2,
    const float* __restrict__ b_ih2, const float* __restrict__ b_hh2,
    const float* __restrict__ W_lin, const float* __restrict__ b_lin,
    float* __restrict__ out)
{
    __shared__ float xs[TT * NB];                                       // 32 KB
    __shared__ __attribute__((aligned(16))) unsigned short vh[2][2048];  // 8 KB
    __shared__ __attribute__((aligned(16))) unsigned short vl[2][2048];  // 8 KB

    const int tid  = threadIdx.x;
    const int w    = tid >> 6;       // wave 0..15
    const int L    = tid & 63;
    const int quad = L >> 4;
    const int n15  = L & 15;
    const int b0g  = blockIdx.x * NB;

    const bool work = (w < NTILE);       // waves 0..12 own tile m = w
    const int  m    = w;
    const int  u    = m * 4 + quad;      // unit this lane updates
    const bool updA = work && (u < HH) && (n15 < NB);
    const bool ldB  = work && (n15 < NB);
    // wave 15 stages x(t+1) each step
    const bool xw   = (w == 15) && (L < NB);

    for (int i = tid; i < 2 * 2048; i += NT) { ((unsigned short*)vh)[i] = 0; ((unsigned short*)vl)[i] = 0; }
    for (int i = tid; i < NB * TT; i += NT) {   // stage x transposed xs[t][b]
        int b = i >> 10, t = i & 1023;
        xs[t * NB + b] = x[(size_t)b0g * TT + i];
    }

    // ---- per-wave A-frags (one tile), biases, cell state ----
    bf16x8 a1h[2], a1l[2], a2h[4], a2l[4];
    f32x4 bias1 = {0.f, 0.f, 0.f, 0.f}, bias2 = {0.f, 0.f, 0.f, 0.f};
    float c1 = 0.f, c2 = 0.f;

    if (work) {
        const int arow = m * 16 + n15;
        const bool av = (arow < 200);
        const int r = av ? ((arow & 3) * 50 + (arow >> 2)) : 0;  // type*50+unit
        #pragma unroll
        for (int kt = 0; kt < 2; ++kt) {    // L1 A: k=0 -> W_ih1, k in [1,50] -> W_hh1
            ushort8 th, tl;
            #pragma unroll
            for (int j = 0; j < 8; ++j) {
                int k = kt * 32 + quad * 8 + j;
                float wv = 0.f;
                if (av) { if (k == 0) wv = W_ih1[r]; else if (k <= 50) wv = W_hh1[r * 50 + k - 1]; }
                unsigned short hh = bf16_rne(wv);
                th[j] = hh; tl[j] = bf16_rne(wv - bf16_tof(hh));
            }
            a1h[kt] = __builtin_bit_cast(bf16x8, th);
            a1l[kt] = __builtin_bit_cast(bf16x8, tl);
        }
        #pragma unroll
        for (int kt = 0; kt < 4; ++kt) {    // L2 A: k 1..50 -> W_ih2, 51..100 -> W_hh2
            ushort8 th, tl;
            #pragma unroll
            for (int j = 0; j < 8; ++j) {
                int k = kt * 32 + quad * 8 + j;
                float wv = 0.f;
                if (av) {
                    if (k >= 1 && k <= 50) wv = W_ih2[r * 50 + k - 1];
                    else if (k >= 51 && k <= 100) wv = W_hh2[r * 50 + k - 51];
                }
                unsigned short hh = bf16_rne(wv);
                th[j] = hh; tl[j] = bf16_rne(wv - bf16_tof(hh));
            }
            a2h[kt] = __builtin_bit_cast(bf16x8, th);
            a2l[kt] = __builtin_bit_cast(bf16x8, tl);
        }
        #pragma unroll
        for (int reg = 0; reg < 4; ++reg) {
            int crow = m * 16 + quad * 4 + reg;
            if (crow < 200) {
                int rr = (crow & 3) * 50 + (crow >> 2);
                bias1[reg] = b_ih1[rr] + b_hh1[rr];
                bias2[reg] = b_ih2[rr] + b_hh2[rr];
            }
        }
    }

    __syncthreads();
    if (tid < NB) {                       // x(0) into buf0 slot k=0
        float xv = xs[0 * NB + tid];
        unsigned short hh = bf16_rne(xv);
        vh[0][vidx(0, tid)] = hh;
        vl[0][vidx(0, tid)] = bf16_rne(xv - bf16_tof(hh));
    }
    __syncthreads();

    bf16x8 bh[4], bl[4];
    #pragma unroll
    for (int kt = 0; kt < 4; ++kt) {
        bh[kt] = __builtin_bit_cast(bf16x8, ushort8{0,0,0,0,0,0,0,0});
        bl[kt] = __builtin_bit_cast(bf16x8, ushort8{0,0,0,0,0,0,0,0});
    }

    // one step: reads vhr/vlr, writes h into vhw/vlw. lastOnly = L2-only tail.
    auto body = [&](int t, const unsigned short* vhr, const unsigned short* vlr,
                    unsigned short* vhw, unsigned short* vlw, bool lastOnly) {
        if (ldB) {
            #pragma unroll
            for (int kt = 0; kt < 4; ++kt) {
                bh[kt] = ((const bf16x8*)vhr)[kt * 64 + L];
                bl[kt] = ((const bf16x8*)vlr)[kt * 64 + L];
            }
        }
        if (work) {
            if (!lastOnly) {
                f32x4 a = bias1;                       // L1 gates(t)
                #pragma unroll
                for (int kt = 0; kt < 2; ++kt) {
                    a = __builtin_amdgcn_mfma_f32_16x16x32_bf16(a1h[kt], bh[kt], a, 0, 0, 0);
                    a = __builtin_amdgcn_mfma_f32_16x16x32_bf16(a1h[kt], bl[kt], a, 0, 0, 0);
                    a = __builtin_amdgcn_mfma_f32_16x16x32_bf16(a1l[kt], bh[kt], a, 0, 0, 0);
                }
                if (updA) {
                    float cn = sigm(a[1]) * c1 + sigm(a[0]) * ftanh(a[2]);
                    c1 = cn;
                    float h = sigm(a[3]) * ftanh(cn);
                    unsigned short hh = bf16_rne(h);
                    unsigned short hl = bf16_rne(h - bf16_tof(hh));
                    vhw[vidx(1 + u, n15)] = hh;
                    vlw[vidx(1 + u, n15)] = hl;
                }
            }
            if (t > 0) {
                f32x4 a = bias2;                       // L2 gates(t-1)
                #pragma unroll
                for (int kt = 0; kt < 4; ++kt) {
                    a = __builtin_amdgcn_mfma_f32_16x16x32_bf16(a2h[kt], bh[kt], a, 0, 0, 0);
                    a = __builtin_amdgcn_mfma_f32_16x16x32_bf16(a2h[kt], bl[kt], a, 0, 0, 0);
                    a = __builtin_amdgcn_mfma_f32_16x16x32_bf16(a2l[kt], bh[kt], a, 0, 0, 0);
                }
                if (updA) {
                    float cn = sigm(a[1]) * c2 + sigm(a[0]) * ftanh(a[2]);
                    c2 = cn;
                    float h = sigm(a[3]) * ftanh(cn);
                    unsigned short hh = bf16_rne(h);
                    unsigned short hl = bf16_rne(h - bf16_tof(hh));
                    vhw[vidx(51 + u, n15)] = hh;
                    vlw[vidx(51 + u, n15)] = hl;
                }
            }
        }
        if (xw && t + 1 < TT) {           // x(t+1) into write buffer slot 0
            float xv = xs[(t + 1) * NB + L];
            unsigned short hh = bf16_rne(xv);
            vhw[vidx(0, L)] = hh;
            vlw[vidx(0, L)] = bf16_rne(xv - bf16_tof(hh));
        }
        __syncthreads();
    };

    // iteration t: L1 gates(t) + L2 gates(t-1); read buf[t&1], write buf[~t&1]
    for (int t = 0; t < TT; t += 2) {
        body(t,     vh[0], vl[0], vh[1], vl[1], false);
        body(t + 1, vh[1], vl[1], vh[0], vl[0], false);
    }
    body(TT, vh[0], vl[0], vh[1], vl[1], true);   // tail: L2 gates(TT-1) only

    // epilogue: h2(T-1) sits in buf1 slots 51..100
    if (tid < NB) {
        float s = b_lin[0];
        #pragma unroll
        for (int uu = 0; uu < HH; ++uu) {
            int id = vidx(51 + uu, tid);
            s += W_lin[uu] * (bf16_tof(vh[1][id]) + bf16_tof(vl[1][id]));
        }
        out[b0g + tid] = s;
    }
}

extern "C" void kernel_launch(void* const* d_in, const int* in_sizes, int n_in,
                              void* d_out, int out_size, void* d_ws, size_t ws_size,
                              hipStream_t stream) {
    const float* x     = (const float*)d_in[0];
    const float* W_ih1 = (const float*)d_in[1];
    const float* W_hh1 = (const float*)d_in[2];
    const float* b_ih1 = (const float*)d_in[3];
    const float* b_hh1 = (const float*)d_in[4];
    const float* W_ih2 = (const float*)d_in[5];
    const float* W_hh2 = (const float*)d_in[6];
    const float* b_ih2 = (const float*)d_in[7];
    const float* b_hh2 = (const float*)d_in[8];
    const float* W_lin = (const float*)d_in[9];
    const float* b_lin = (const float*)d_in[10];
    float* out = (float*)d_out;

    const int Btot = in_sizes[0] / TT;   // 2048
    const int nblocks = Btot / NB;       // 256 -> 1 block/CU

    lstm_kernel<<<nblocks, NT, 0, stream>>>(
        x, W_ih1, W_hh1, b_ih1, b_hh1, W_ih2, W_hh2, b_ih2, b_hh2,
        W_lin, b_lin, out);
}

// Round 6
// 903.379 us; speedup vs baseline: 8.3315x; 1.2591x over previous
//
#include <hip/hip_runtime.h>

// LSTM_76622216560744: 2-layer LSTM (H=50), B=2048, T=1024, input dim 1.
// R6: split-bf16 MFMA (16x16x32), M=200 gate rows (row'=unit*4+type), N=16
// (8 real batches), combined K=128 B-operand [x | h1 | h2 | pad]. 16 waves
// (4/SIMD), one M-tile per wave (waves 0..12 work, wave 15 stages x).
// NEW: both layers' cell updates merged into ONE full-lane update — L2 accs
// swizzled (lane xor 8) into the idle n15>=8 half, single shared trans chain
// (5 exp + 5 rcp instead of 10+10), unified c register. 1 barrier/step.

#define TT 1024
#define HH 50
#define NB 8     // real batches per block
#define NT 1024  // 16 waves, 4 per SIMD
#define NTILE 13 // ceil(200/16) M-tiles

typedef __bf16 bf16x8 __attribute__((ext_vector_type(8)));
typedef unsigned short ushort8 __attribute__((ext_vector_type(8)));
typedef float f32x4 __attribute__((ext_vector_type(4)));

__device__ __forceinline__ unsigned short bf16_rne(float f) {
    unsigned u = __float_as_uint(f);
    return (unsigned short)((u + 0x7fffu + ((u >> 16) & 1u)) >> 16);
}
__device__ __forceinline__ float bf16_tof(unsigned short h) {
    return __uint_as_float((unsigned)h << 16);
}
__device__ __forceinline__ float fast_rcp(float x) { return __builtin_amdgcn_rcpf(x); }
__device__ __forceinline__ float sigm(float x) { return fast_rcp(1.0f + __expf(-x)); }
__device__ __forceinline__ float ftanh(float x) {
    float e = __expf(-2.0f * x);
    return (1.0f - e) * fast_rcp(1.0f + e);
}
__device__ __forceinline__ float lane_swap8(float v) {
    // BitMode swizzle: and=0x1F, or=0, xor=8 -> lane L <-> L^8
    return __int_as_float(__builtin_amdgcn_ds_swizzle(__float_as_int(v), 0x201F));
}

// frag-ready blocked layout: idx = (k>>3)*128 + n*8 + (k&7), k<128, n<16
__device__ __forceinline__ int vidx(int k, int n) {
    return ((k >> 3) << 7) + n * 8 + (k & 7);
}

__global__ __launch_bounds__(NT) void lstm_kernel(
    const float* __restrict__ x,
    const float* __restrict__ W_ih1, const float* __restrict__ W_hh1,
    const float* __restrict__ b_ih1, const float* __restrict__ b_hh1,
    const float* __restrict__ W_ih2, const float* __restrict__ W_hh2,
    const float* __restrict__ b_ih2, const float* __restrict__ b_hh2,
    const float* __restrict__ W_lin, const float* __restrict__ b_lin,
    float* __restrict__ out)
{
    __shared__ float xs[TT * NB];                                       // 32 KB
    __shared__ __attribute__((aligned(16))) unsigned short vh[2][2048];  // 8 KB
    __shared__ __attribute__((aligned(16))) unsigned short vl[2][2048];  // 8 KB

    const int tid  = threadIdx.x;
    const int w    = tid >> 6;       // wave 0..15
    const int L    = tid & 63;
    const int quad = L >> 4;
    const int n15  = L & 15;
    const int b0g  = blockIdx.x * NB;

    const bool work = (w < NTILE);       // waves 0..12 own tile m = w
    const int  m    = w;
    const int  u    = m * 4 + quad;      // unit this lane updates
    const bool low  = (n15 < NB);        // low half: L1 update / B loads
    const bool updOK = work && (u < HH); // all 64 lanes update (L1 low, L2 high)
    const bool ldB  = work && low;
    const bool xw   = (w == 15) && (L < NB);   // wave 15 stages x(t+1)
    // this lane's h slot: low half -> h1 (k=1+u), high half -> h2 (k=51+u)
    const int hslot = low ? vidx(1 + u, n15) : vidx(51 + u, n15 - NB);

    for (int i = tid; i < 2 * 2048; i += NT) { ((unsigned short*)vh)[i] = 0; ((unsigned short*)vl)[i] = 0; }
    for (int i = tid; i < NB * TT; i += NT) {   // stage x transposed xs[t][b]
        int b = i >> 10, t = i & 1023;
        xs[t * NB + b] = x[(size_t)b0g * TT + i];
    }

    // ---- per-wave A-frags (one tile), biases, unified cell state ----
    bf16x8 a1h[2], a1l[2], a2h[4], a2l[4];
    f32x4 bias1 = {0.f, 0.f, 0.f, 0.f}, bias2 = {0.f, 0.f, 0.f, 0.f};
    float c = 0.f;    // low lanes: c1, high lanes: c2

    if (work) {
        const int arow = m * 16 + n15;
        const bool av = (arow < 200);
        const int r = av ? ((arow & 3) * 50 + (arow >> 2)) : 0;  // type*50+unit
        #pragma unroll
        for (int kt = 0; kt < 2; ++kt) {    // L1 A: k=0 -> W_ih1, k in [1,50] -> W_hh1
            ushort8 th, tl;
            #pragma unroll
            for (int j = 0; j < 8; ++j) {
                int k = kt * 32 + quad * 8 + j;
                float wv = 0.f;
                if (av) { if (k == 0) wv = W_ih1[r]; else if (k <= 50) wv = W_hh1[r * 50 + k - 1]; }
                unsigned short hh = bf16_rne(wv);
                th[j] = hh; tl[j] = bf16_rne(wv - bf16_tof(hh));
            }
            a1h[kt] = __builtin_bit_cast(bf16x8, th);
            a1l[kt] = __builtin_bit_cast(bf16x8, tl);
        }
        #pragma unroll
        for (int kt = 0; kt < 4; ++kt) {    // L2 A: k 1..50 -> W_ih2, 51..100 -> W_hh2
            ushort8 th, tl;
            #pragma unroll
            for (int j = 0; j < 8; ++j) {
                int k = kt * 32 + quad * 8 + j;
                float wv = 0.f;
                if (av) {
                    if (k >= 1 && k <= 50) wv = W_ih2[r * 50 + k - 1];
                    else if (k >= 51 && k <= 100) wv = W_hh2[r * 50 + k - 51];
                }
                unsigned short hh = bf16_rne(wv);
                th[j] = hh; tl[j] = bf16_rne(wv - bf16_tof(hh));
            }
            a2h[kt] = __builtin_bit_cast(bf16x8, th);
            a2l[kt] = __builtin_bit_cast(bf16x8, tl);
        }
        #pragma unroll
        for (int reg = 0; reg < 4; ++reg) {
            int crow = m * 16 + quad * 4 + reg;
            if (crow < 200) {
                int rr = (crow & 3) * 50 + (crow >> 2);
                bias1[reg] = b_ih1[rr] + b_hh1[rr];
                bias2[reg] = b_ih2[rr] + b_hh2[rr];
            }
        }
    }

    __syncthreads();
    if (tid < NB) {                       // x(0) into buf0 slot k=0
        float xv = xs[0 * NB + tid];
        unsigned short hh = bf16_rne(xv);
        vh[0][vidx(0, tid)] = hh;
        vl[0][vidx(0, tid)] = bf16_rne(xv - bf16_tof(hh));
    }
    __syncthreads();

    bf16x8 bh[4], bl[4];
    #pragma unroll
    for (int kt = 0; kt < 4; ++kt) {
        bh[kt] = __builtin_bit_cast(bf16x8, ushort8{0,0,0,0,0,0,0,0});
        bl[kt] = __builtin_bit_cast(bf16x8, ushort8{0,0,0,0,0,0,0,0});
    }

    // one step: iter t = L1 gates(t) + L2 gates(t-1); read vhr, write vhw.
    auto body = [&](int t, const unsigned short* vhr, const unsigned short* vlr,
                    unsigned short* vhw, unsigned short* vlw,
                    bool doL1, bool doL2) {
        if (ldB) {
            #pragma unroll
            for (int kt = 0; kt < 4; ++kt) {
                bh[kt] = ((const bf16x8*)vhr)[kt * 64 + L];
                bl[kt] = ((const bf16x8*)vlr)[kt * 64 + L];
            }
        }
        if (work) {
            f32x4 acc1 = bias1, acc2 = bias2;
            if (doL1) {
                #pragma unroll
                for (int kt = 0; kt < 2; ++kt) {
                    acc1 = __builtin_amdgcn_mfma_f32_16x16x32_bf16(a1h[kt], bh[kt], acc1, 0, 0, 0);
                    acc1 = __builtin_amdgcn_mfma_f32_16x16x32_bf16(a1h[kt], bl[kt], acc1, 0, 0, 0);
                    acc1 = __builtin_amdgcn_mfma_f32_16x16x32_bf16(a1l[kt], bh[kt], acc1, 0, 0, 0);
                }
            }
            if (doL2) {
                #pragma unroll
                for (int kt = 0; kt < 4; ++kt) {
                    acc2 = __builtin_amdgcn_mfma_f32_16x16x32_bf16(a2h[kt], bh[kt], acc2, 0, 0, 0);
                    acc2 = __builtin_amdgcn_mfma_f32_16x16x32_bf16(a2h[kt], bl[kt], acc2, 0, 0, 0);
                    acc2 = __builtin_amdgcn_mfma_f32_16x16x32_bf16(a2l[kt], bh[kt], acc2, 0, 0, 0);
                }
            }
            // merge: low lanes take L1 acc, high lanes take partner's L2 acc
            f32x4 g;
            #pragma unroll
            for (int r = 0; r < 4; ++r) {
                float sw = lane_swap8(acc2[r]);
                g[r] = low ? acc1[r] : sw;
            }
            // shared cell update (one trans chain for both layers)
            if (updOK && (doL2 || low)) {
                float cn = sigm(g[1]) * c + sigm(g[0]) * ftanh(g[2]);
                c = cn;
                float h = sigm(g[3]) * ftanh(cn);
                unsigned short hh = bf16_rne(h);
                unsigned short hl = bf16_rne(h - bf16_tof(hh));
                vhw[hslot] = hh;
                vlw[hslot] = hl;
            }
        }
        if (xw && t + 1 < TT) {           // x(t+1) into write buffer slot 0
            float xv = xs[(t + 1) * NB + L];
            unsigned short hh = bf16_rne(xv);
            vhw[vidx(0, L)] = hh;
            vlw[vidx(0, L)] = bf16_rne(xv - bf16_tof(hh));
        }
        __syncthreads();
    };

    // peel t=0 (no L2 yet: keep high-half c untouched), steady pairs, tail.
    body(0, vh[0], vl[0], vh[1], vl[1], true, false);
    body(1, vh[1], vl[1], vh[0], vl[0], true, true);
    for (int t = 2; t < TT; t += 2) {
        body(t,     vh[0], vl[0], vh[1], vl[1], true, true);
        body(t + 1, vh[1], vl[1], vh[0], vl[0], true, true);
    }
    // tail: L2 gates(TT-1) only; low-half writes h1/c1 garbage -> provably dead
    body(TT, vh[0], vl[0], vh[1], vl[1], false, true);

    // epilogue: h2(T-1) sits in buf1 slots 51..100
    if (tid < NB) {
        float s = b_lin[0];
        #pragma unroll
        for (int uu = 0; uu < HH; ++uu) {
            int id = vidx(51 + uu, tid);
            s += W_lin[uu] * (bf16_tof(vh[1][id]) + bf16_tof(vl[1][id]));
        }
        out[b0g + tid] = s;
    }
}

extern "C" void kernel_launch(void* const* d_in, const int* in_sizes, int n_in,
                              void* d_out, int out_size, void* d_ws, size_t ws_size,
                              hipStream_t stream) {
    const float* x     = (const float*)d_in[0];
    const float* W_ih1 = (const float*)d_in[1];
    const float* W_hh1 = (const float*)d_in[2];
    const float* b_ih1 = (const float*)d_in[3];
    const float* b_hh1 = (const float*)d_in[4];
    const float* W_ih2 = (const float*)d_in[5];
    const float* W_hh2 = (const float*)d_in[6];
    const float* b_ih2 = (const float*)d_in[7];
    const float* b_hh2 = (const float*)d_in[8];
    const float* W_lin = (const float*)d_in[9];
    const float* b_lin = (const float*)d_in[10];
    float* out = (float*)d_out;

    const int Btot = in_sizes[0] / TT;   // 2048
    const int nblocks = Btot / NB;       // 256 -> 1 block/CU

    lstm_kernel<<<nblocks, NT, 0, stream>>>(
        x, W_ih1, W_hh1, b_ih1, b_hh1, W_ih2, W_hh2, b_ih2, b_hh2,
        W_lin, b_lin, out);
}

// Round 7
// 707.255 us; speedup vs baseline: 10.6419x; 1.2773x over previous
//
#include <hip/hip_runtime.h>

// LSTM_76622216560744: 2-layer LSTM (H=50), B=2048, T=1024, input dim 1.
// R7: fp16 MFMA (16x16x32_f16). M=200 gate rows (row'=unit*4+type), N=16
// (8 real batches), combined K=128 B-operand [x | h1 | h2 | pad]. 16 waves
// (4/SIMD), one M-tile per wave (waves 0..12 work, wave 15 stages x).
// Weights: hi fp16 + residual*2^11 fp16 (subnormal-safe) in a SEPARATE
// correction accumulator, combined g = accM + accC/2048 -> 2 MFMA products
// instead of 3. h/x stored single fp16 (2^-12 rel err). g-gate rows
// pre-scaled by 2 (tanh fold). Shared-denominator update: 5 exp + 3 rcp.
// L2 accs swizzled (lane xor 8) into idle half -> one full-lane update.
// Double-buffered v, 1 barrier/step.

#define TT 1024
#define HH 50
#define NB 8     // real batches per block
#define NT 1024  // 16 waves, 4 per SIMD
#define NTILE 13 // ceil(200/16) M-tiles

typedef _Float16 f16x8 __attribute__((ext_vector_type(8)));
typedef unsigned short ushort8 __attribute__((ext_vector_type(8)));
typedef float f32x4 __attribute__((ext_vector_type(4)));

__device__ __forceinline__ float fast_rcp(float x) { return __builtin_amdgcn_rcpf(x); }
__device__ __forceinline__ float lane_swap8(float v) {
    // BitMode swizzle: and=0x1F, or=0, xor=8 -> lane L <-> L^8
    return __int_as_float(__builtin_amdgcn_ds_swizzle(__float_as_int(v), 0x201F));
}
__device__ __forceinline__ unsigned short f16bits(float f) {
    _Float16 h = (_Float16)f;                 // v_cvt_f16_f32 (RNE)
    return __builtin_bit_cast(unsigned short, h);
}
__device__ __forceinline__ float f16tof(unsigned short b) {
    return (float)__builtin_bit_cast(_Float16, b);
}

// frag-ready blocked layout: idx = (k>>3)*128 + n*8 + (k&7), k<128, n<16
__device__ __forceinline__ int vidx(int k, int n) {
    return ((k >> 3) << 7) + n * 8 + (k & 7);
}

__global__ __launch_bounds__(NT) void lstm_kernel(
    const float* __restrict__ x,
    const float* __restrict__ W_ih1, const float* __restrict__ W_hh1,
    const float* __restrict__ b_ih1, const float* __restrict__ b_hh1,
    const float* __restrict__ W_ih2, const float* __restrict__ W_hh2,
    const float* __restrict__ b_ih2, const float* __restrict__ b_hh2,
    const float* __restrict__ W_lin, const float* __restrict__ b_lin,
    float* __restrict__ out)
{
    __shared__ float xs[TT * NB];                                      // 32 KB
    __shared__ __attribute__((aligned(16))) unsigned short v[2][2048]; // 8 KB

    const int tid  = threadIdx.x;
    const int w    = tid >> 6;       // wave 0..15
    const int L    = tid & 63;
    const int quad = L >> 4;
    const int n15  = L & 15;
    const int b0g  = blockIdx.x * NB;

    const bool work  = (w < NTILE);      // waves 0..12 own tile m = w
    const int  m     = w;
    const int  u     = m * 4 + quad;     // unit this lane updates
    const bool low   = (n15 < NB);       // low half: L1 update / B loads
    const bool updOK = work && (u < HH);
    const bool ldB   = work && low;
    const bool xw    = (w == 15) && (L < NB);  // wave 15 stages x(t+1)
    // this lane's h slot: low half -> h1 (k=1+u), high half -> h2 (k=51+u)
    const int hslot = low ? vidx(1 + u, n15) : vidx(51 + u, n15 - NB);

    for (int i = tid; i < 2 * 2048; i += NT) ((unsigned short*)v)[i] = 0;
    for (int i = tid; i < NB * TT; i += NT) {   // stage x transposed xs[t][b]
        int b = i >> 10, t = i & 1023;
        xs[t * NB + b] = x[(size_t)b0g * TT + i];
    }

    // ---- per-wave A-frags: hi fp16 + residual*2^11 fp16 ----
    f16x8 a1h[2], a1c[2], a2h[4], a2c[4];
    f32x4 bias1 = {0.f, 0.f, 0.f, 0.f}, bias2 = {0.f, 0.f, 0.f, 0.f};
    float c = 0.f;    // low lanes: c1, high lanes: c2

    if (work) {
        const int arow = m * 16 + n15;
        const bool av = (arow < 200);
        const int r = av ? ((arow & 3) * 50 + (arow >> 2)) : 0;  // type*50+unit
        const float sc = (av && (arow & 3) == 2) ? 2.0f : 1.0f;  // g-row tanh fold
        #pragma unroll
        for (int kt = 0; kt < 2; ++kt) {    // L1 A: k=0 -> W_ih1, k in [1,50] -> W_hh1
            ushort8 th, tc;
            #pragma unroll
            for (int j = 0; j < 8; ++j) {
                int k = kt * 32 + quad * 8 + j;
                float wv = 0.f;
                if (av) { if (k == 0) wv = W_ih1[r]; else if (k <= 50) wv = W_hh1[r * 50 + k - 1]; }
                wv *= sc;
                unsigned short hb = f16bits(wv);
                th[j] = hb; tc[j] = f16bits((wv - f16tof(hb)) * 2048.0f);
            }
            a1h[kt] = __builtin_bit_cast(f16x8, th);
            a1c[kt] = __builtin_bit_cast(f16x8, tc);
        }
        #pragma unroll
        for (int kt = 0; kt < 4; ++kt) {    // L2 A: k 1..50 -> W_ih2, 51..100 -> W_hh2
            ushort8 th, tc;
            #pragma unroll
            for (int j = 0; j < 8; ++j) {
                int k = kt * 32 + quad * 8 + j;
                float wv = 0.f;
                if (av) {
                    if (k >= 1 && k <= 50) wv = W_ih2[r * 50 + k - 1];
                    else if (k >= 51 && k <= 100) wv = W_hh2[r * 50 + k - 51];
                }
                wv *= sc;
                unsigned short hb = f16bits(wv);
                th[j] = hb; tc[j] = f16bits((wv - f16tof(hb)) * 2048.0f);
            }
            a2h[kt] = __builtin_bit_cast(f16x8, th);
            a2c[kt] = __builtin_bit_cast(f16x8, tc);
        }
        #pragma unroll
        for (int reg = 0; reg < 4; ++reg) {
            int crow = m * 16 + quad * 4 + reg;
            if (crow < 200) {
                int rr = (crow & 3) * 50 + (crow >> 2);
                float s2 = ((crow & 3) == 2) ? 2.0f : 1.0f;
                bias1[reg] = s2 * (b_ih1[rr] + b_hh1[rr]);
                bias2[reg] = s2 * (b_ih2[rr] + b_hh2[rr]);
            }
        }
    }

    __syncthreads();
    if (tid < NB) v[0][vidx(0, tid)] = f16bits(xs[0 * NB + tid]);  // x(0)
    __syncthreads();

    f16x8 bfr[4];
    #pragma unroll
    for (int kt = 0; kt < 4; ++kt)
        bfr[kt] = __builtin_bit_cast(f16x8, ushort8{0,0,0,0,0,0,0,0});

    const f32x4 zero4 = {0.f, 0.f, 0.f, 0.f};

    // one step: iter t = L1 gates(t) + L2 gates(t-1); read vr, write vw.
    auto body = [&](int t, const unsigned short* vr, unsigned short* vw,
                    bool doL1, bool doL2) {
        if (ldB) {
            #pragma unroll
            for (int kt = 0; kt < 4; ++kt)
                bfr[kt] = ((const f16x8*)vr)[kt * 64 + L];
        }
        if (work) {
            f32x4 aM1 = bias1, aC1 = zero4, aM2 = bias2, aC2 = zero4;
            if (doL1) {
                #pragma unroll
                for (int kt = 0; kt < 2; ++kt) {
                    aM1 = __builtin_amdgcn_mfma_f32_16x16x32_f16(a1h[kt], bfr[kt], aM1, 0, 0, 0);
                    aC1 = __builtin_amdgcn_mfma_f32_16x16x32_f16(a1c[kt], bfr[kt], aC1, 0, 0, 0);
                }
            }
            if (doL2) {
                #pragma unroll
                for (int kt = 0; kt < 4; ++kt) {
                    aM2 = __builtin_amdgcn_mfma_f32_16x16x32_f16(a2h[kt], bfr[kt], aM2, 0, 0, 0);
                    aC2 = __builtin_amdgcn_mfma_f32_16x16x32_f16(a2c[kt], bfr[kt], aC2, 0, 0, 0);
                }
            }
            // combine hi + residual/2048; low lanes keep L1, high take L2^8
            f32x4 g;
            #pragma unroll
            for (int r = 0; r < 4; ++r) {
                float g2 = lane_swap8(fmaf(aC2[r], 4.8828125e-4f, aM2[r]));
                float g1 = fmaf(aC1[r], 4.8828125e-4f, aM1[r]);
                g[r] = low ? g1 : g2;
            }
            // shared cell update: gates (i, f, g*, o), g* pre-scaled by 2
            if (updOK && (doL2 || low)) {
                float ei = __expf(-g[0]);
                float ef = __expf(-g[1]);
                float eg = __expf(-g[2]);          // e^(-2*gg)
                float eo = __expf(-g[3]);
                float sf = fast_rcp(1.0f + ef);
                float sc_t = (1.0f - eg) * fast_rcp((1.0f + ei) * (1.0f + eg)); // sig(i)*tanh(gg)
                float cn = fmaf(sf, c, sc_t);
                c = cn;
                float ecn = __expf(-2.0f * cn);
                float h = (1.0f - ecn) * fast_rcp((1.0f + eo) * (1.0f + ecn));
                vw[hslot] = f16bits(h);
            }
        }
        if (xw && t + 1 < TT) vw[vidx(0, L)] = f16bits(xs[(t + 1) * NB + L]);
        __syncthreads();
    };

    // peel t=0 (no L2 yet: high-half c untouched), steady pairs, tail.
    body(0, v[0], v[1], true, false);
    body(1, v[1], v[0], true, true);
    for (int t = 2; t < TT; t += 2) {
        body(t,     v[0], v[1], true, true);
        body(t + 1, v[1], v[0], true, true);
    }
    // tail: L2 gates(TT-1) only; low-half h1/c1 writes are dead
    body(TT, v[0], v[1], false, true);

    // epilogue: h2(T-1) sits in buf1 slots 51..100
    if (tid < NB) {
        float s = b_lin[0];
        #pragma unroll
        for (int uu = 0; uu < HH; ++uu)
            s += W_lin[uu] * f16tof(v[1][vidx(51 + uu, tid)]);
        out[b0g + tid] = s;
    }
}

extern "C" void kernel_launch(void* const* d_in, const int* in_sizes, int n_in,
                              void* d_out, int out_size, void* d_ws, size_t ws_size,
                              hipStream_t stream) {
    const float* x     = (const float*)d_in[0];
    const float* W_ih1 = (const float*)d_in[1];
    const float* W_hh1 = (const float*)d_in[2];
    const float* b_ih1 = (const float*)d_in[3];
    const float* b_hh1 = (const float*)d_in[4];
    const float* W_ih2 = (const float*)d_in[5];
    const float* W_hh2 = (const float*)d_in[6];
    const float* b_ih2 = (const float*)d_in[7];
    const float* b_hh2 = (const float*)d_in[8];
    const float* W_lin = (const float*)d_in[9];
    const float* b_lin = (const float*)d_in[10];
    float* out = (float*)d_out;

    const int Btot = in_sizes[0] / TT;   // 2048
    const int nblocks = Btot / NB;       // 256 -> 1 block/CU

    lstm_kernel<<<nblocks, NT, 0, stream>>>(
        x, W_ih1, W_hh1, b_ih1, b_hh1, W_ih2, W_hh2, b_ih2, b_hh2,
        W_lin, b_lin, out);
}

// Round 8
// 549.388 us; speedup vs baseline: 13.6999x; 1.2874x over previous
//
#include <hip/hip_runtime.h>

// LSTM_76622216560744: 2-layer LSTM (H=50), B=2048, T=1024, input dim 1.
// R8: straight fp16 MFMA (16x16x32_f16), no residual correction (fp16 weight
// rounding analysis: steady-state error ~3e-5, below the 2^-12 h-storage
// floor). M=200 gate rows (row'=unit*4+type), N=16 (8 real batches),
// combined K=128 B-operand [x | h1 | h2 | pad]. 13 waves (NT=832), one
// M-tile per wave; x staged by wave 12's update-idle lanes (quad 2).
// Weights/biases pre-scaled by -log2e (-2log2e for g rows) so v_exp_f32 is
// used raw. L2 accs swizzled (lane xor 8) into the idle N-half -> one
// full-lane update chain (4 exp + 1 exp + 3 rcp). Double-buffered v,
// 1 barrier/step.

#define TT 1024
#define HH 50
#define NB 8     // real batches per block
#define NT 832   // 13 waves
#define NTILE 13 // ceil(200/16) M-tiles

typedef _Float16 f16x8 __attribute__((ext_vector_type(8)));
typedef unsigned short ushort8 __attribute__((ext_vector_type(8)));
typedef float f32x4 __attribute__((ext_vector_type(4)));

#define NLOG2E  -1.4426950408889634f   // -log2(e)
#define N2LOG2E -2.8853900817779268f   // -2*log2(e)

__device__ __forceinline__ float fast_rcp(float x) { return __builtin_amdgcn_rcpf(x); }
__device__ __forceinline__ float exp2f_hw(float x) { return __builtin_amdgcn_exp2f(x); }
__device__ __forceinline__ float lane_swap8(float v) {
    // BitMode swizzle: and=0x1F, or=0, xor=8 -> lane L <-> L^8
    return __int_as_float(__builtin_amdgcn_ds_swizzle(__float_as_int(v), 0x201F));
}
__device__ __forceinline__ unsigned short f16bits(float f) {
    _Float16 h = (_Float16)f;                 // v_cvt_f16_f32 (RNE)
    return __builtin_bit_cast(unsigned short, h);
}
__device__ __forceinline__ float f16tof(unsigned short b) {
    return (float)__builtin_bit_cast(_Float16, b);
}

// frag-ready blocked layout: idx = (k>>3)*128 + n*8 + (k&7), k<128, n<16
__device__ __forceinline__ int vidx(int k, int n) {
    return ((k >> 3) << 7) + n * 8 + (k & 7);
}

__global__ __launch_bounds__(NT) void lstm_kernel(
    const float* __restrict__ x,
    const float* __restrict__ W_ih1, const float* __restrict__ W_hh1,
    const float* __restrict__ b_ih1, const float* __restrict__ b_hh1,
    const float* __restrict__ W_ih2, const float* __restrict__ W_hh2,
    const float* __restrict__ b_ih2, const float* __restrict__ b_hh2,
    const float* __restrict__ W_lin, const float* __restrict__ b_lin,
    float* __restrict__ out)
{
    __shared__ float xs[TT * NB];                                      // 32 KB
    __shared__ __attribute__((aligned(16))) unsigned short v[2][2048]; // 8 KB

    const int tid  = threadIdx.x;
    const int w    = tid >> 6;       // wave 0..12
    const int L    = tid & 63;
    const int quad = L >> 4;
    const int n15  = L & 15;
    const int b0g  = blockIdx.x * NB;

    const int  m     = w;                // tile per wave
    const int  u     = m * 4 + quad;     // unit this lane updates
    const bool low   = (n15 < NB);       // low half: L1 update / B loads
    const bool updOK = (u < HH);
    const bool ldB   = low;
    // wave 12's quad-2 lanes (u=50, update-idle) stage x(t+1)
    const bool xw    = (w == 12) && (L >= 32) && (L < 32 + NB);
    const int  xb    = L - 32;
    // this lane's h slot: low half -> h1 (k=1+u), high half -> h2 (k=51+u)
    const int hslot = low ? vidx(1 + u, n15) : vidx(51 + u, n15 - NB);

    for (int i = tid; i < 2 * 2048; i += NT) ((unsigned short*)v)[i] = 0;
    for (int i = tid; i < NB * TT; i += NT) {   // stage x transposed xs[t][b]
        int b = i >> 10, t = i & 1023;
        xs[t * NB + b] = x[(size_t)b0g * TT + i];
    }

    // ---- per-wave A-frags: fp16, pre-scaled by -log2e (g rows: -2log2e) ----
    f16x8 a1[2], a2[4];
    f32x4 bias1 = {0.f, 0.f, 0.f, 0.f}, bias2 = {0.f, 0.f, 0.f, 0.f};
    float c = 0.f;    // low lanes: c1, high lanes: c2

    {
        const int arow = m * 16 + n15;
        const bool av = (arow < 200);
        const int r = av ? ((arow & 3) * 50 + (arow >> 2)) : 0;  // type*50+unit
        const float sc = ((arow & 3) == 2) ? N2LOG2E : NLOG2E;
        #pragma unroll
        for (int kt = 0; kt < 2; ++kt) {    // L1 A: k=0 -> W_ih1, k in [1,50] -> W_hh1
            ushort8 th;
            #pragma unroll
            for (int j = 0; j < 8; ++j) {
                int k = kt * 32 + quad * 8 + j;
                float wv = 0.f;
                if (av) { if (k == 0) wv = W_ih1[r]; else if (k <= 50) wv = W_hh1[r * 50 + k - 1]; }
                th[j] = f16bits(wv * sc);
            }
            a1[kt] = __builtin_bit_cast(f16x8, th);
        }
        #pragma unroll
        for (int kt = 0; kt < 4; ++kt) {    // L2 A: k 1..50 -> W_ih2, 51..100 -> W_hh2
            ushort8 th;
            #pragma unroll
            for (int j = 0; j < 8; ++j) {
                int k = kt * 32 + quad * 8 + j;
                float wv = 0.f;
                if (av) {
                    if (k >= 1 && k <= 50) wv = W_ih2[r * 50 + k - 1];
                    else if (k >= 51 && k <= 100) wv = W_hh2[r * 50 + k - 51];
                }
                th[j] = f16bits(wv * sc);
            }
            a2[kt] = __builtin_bit_cast(f16x8, th);
        }
        #pragma unroll
        for (int reg = 0; reg < 4; ++reg) {
            int crow = m * 16 + quad * 4 + reg;
            if (crow < 200) {
                int rr = (crow & 3) * 50 + (crow >> 2);
                float s2 = ((crow & 3) == 2) ? N2LOG2E : NLOG2E;
                bias1[reg] = s2 * (b_ih1[rr] + b_hh1[rr]);
                bias2[reg] = s2 * (b_ih2[rr] + b_hh2[rr]);
            }
        }
    }

    __syncthreads();
    if (tid < NB) v[0][vidx(0, tid)] = f16bits(xs[0 * NB + tid]);  // x(0)
    __syncthreads();

    f16x8 bfr[4];
    #pragma unroll
    for (int kt = 0; kt < 4; ++kt)
        bfr[kt] = __builtin_bit_cast(f16x8, ushort8{0,0,0,0,0,0,0,0});

    // one step: iter t = L1 gates(t) + L2 gates(t-1); read vr, write vw.
    // Accumulators hold -g*log2e (g rows: -2g*log2e) -> raw v_exp gives e^-g.
    auto body = [&](int t, const unsigned short* vr, unsigned short* vw,
                    bool doL1, bool doL2) {
        if (ldB) {
            #pragma unroll
            for (int kt = 0; kt < 4; ++kt)
                bfr[kt] = ((const f16x8*)vr)[kt * 64 + L];
        }
        {
            f32x4 aM1 = bias1, aM2 = bias2;
            if (doL1) {
                #pragma unroll
                for (int kt = 0; kt < 2; ++kt)
                    aM1 = __builtin_amdgcn_mfma_f32_16x16x32_f16(a1[kt], bfr[kt], aM1, 0, 0, 0);
            }
            if (doL2) {
                #pragma unroll
                for (int kt = 0; kt < 4; ++kt)
                    aM2 = __builtin_amdgcn_mfma_f32_16x16x32_f16(a2[kt], bfr[kt], aM2, 0, 0, 0);
            }
            // low lanes keep L1 acc; high lanes take partner's L2 acc (xor 8)
            f32x4 g;
            #pragma unroll
            for (int r = 0; r < 4; ++r) {
                float g2 = lane_swap8(aM2[r]);
                g[r] = low ? aM1[r] : g2;
            }
            // shared cell update: g = (-i, -f, -2gg, -o) * log2e
            if (updOK && (doL2 || low)) {
                float ei = exp2f_hw(g[0]);          // e^-i
                float ef = exp2f_hw(g[1]);          // e^-f
                float eg = exp2f_hw(g[2]);          // e^-2gg
                float eo = exp2f_hw(g[3]);          // e^-o
                float sf = fast_rcp(1.0f + ef);
                float sc_t = (1.0f - eg) * fast_rcp((1.0f + ei) * (1.0f + eg));
                float cn = fmaf(sf, c, sc_t);
                c = cn;
                float ecn = exp2f_hw(cn * N2LOG2E); // e^-2c
                float h = (1.0f - ecn) * fast_rcp((1.0f + eo) * (1.0f + ecn));
                vw[hslot] = f16bits(h);
            }
        }
        if (xw && t + 1 < TT) vw[vidx(0, xb)] = f16bits(xs[(t + 1) * NB + xb]);
        __syncthreads();
    };

    // peel t=0 (no L2 yet: high-half c untouched), steady pairs, tail.
    body(0, v[0], v[1], true, false);
    body(1, v[1], v[0], true, true);
    for (int t = 2; t < TT; t += 2) {
        body(t,     v[0], v[1], true, true);
        body(t + 1, v[1], v[0], true, true);
    }
    // tail: L2 gates(TT-1) only; low-half h1/c1 writes are dead
    body(TT, v[0], v[1], false, true);

    // epilogue: h2(T-1) sits in buf1 slots 51..100
    if (tid < NB) {
        float s = b_lin[0];
        #pragma unroll
        for (int uu = 0; uu < HH; ++uu)
            s += W_lin[uu] * f16tof(v[1][vidx(51 + uu, tid)]);
        out[b0g + tid] = s;
    }
}

extern "C" void kernel_launch(void* const* d_in, const int* in_sizes, int n_in,
                              void* d_out, int out_size, void* d_ws, size_t ws_size,
                              hipStream_t stream) {
    const float* x     = (const float*)d_in[0];
    const float* W_ih1 = (const float*)d_in[1];
    const float* W_hh1 = (const float*)d_in[2];
    const float* b_ih1 = (const float*)d_in[3];
    const float* b_hh1 = (const float*)d_in[4];
    const float* W_ih2 = (const float*)d_in[5];
    const float* W_hh2 = (const float*)d_in[6];
    const float* b_ih2 = (const float*)d_in[7];
    const float* b_hh2 = (const float*)d_in[8];
    const float* W_lin = (const float*)d_in[9];
    const float* b_lin = (const float*)d_in[10];
    float* out = (float*)d_out;

    const int Btot = in_sizes[0] / TT;   // 2048
    const int nblocks = Btot / NB;       // 256 -> 1 block/CU

    lstm_kernel<<<nblocks, NT, 0, stream>>>(
        x, W_ih1, W_hh1, b_ih1, b_hh1, W_ih2, W_hh2, b_ih2, b_hh2,
        W_lin, b_lin, out);
}

// Round 9
// 534.095 us; speedup vs baseline: 14.0921x; 1.0286x over previous
//
#include <hip/hip_runtime.h>

// LSTM_76622216560744: 2-layer LSTM (H=50), B=2048, T=1024, input dim 1.
// R9: fp16 MFMA (16x16x32_f16), M=200 gate rows (row'=unit*4+type), N=16
// (8 real batches), combined K=128 B-operand [x | h1 | h2 | pad]. 13 waves,
// one M-tile per wave; x staged by wave 12's quad-2 lanes. Weights/biases
// pre-scaled by -log2e (-2log2e for g rows) -> raw v_exp. L1/L2 acc merge
// via ONE update_dpp (row_shr:8, bank_mask=0xC): lanes 8..15 of each 16-row
// take partner's L2 acc, 0..7 keep L1 acc -- no ds_swizzle, no cndmask.
// Update runs unconditionally on all lanes; invalid lanes write to a dump
// tail (slots 2048+L, outside the k<128 read region). Single-rcp cn
// (5 exp + 2 rcp). Double-buffered v, 1 barrier/step.

#define TT 1024
#define HH 50
#define NB 8     // real batches per block
#define NT 832   // 13 waves
#define NTILE 13 // ceil(200/16) M-tiles
#define VSZ 2112 // 2048 data shorts + 64 dump shorts

typedef _Float16 f16x8 __attribute__((ext_vector_type(8)));
typedef unsigned short ushort8 __attribute__((ext_vector_type(8)));
typedef float f32x4 __attribute__((ext_vector_type(4)));

#define NLOG2E  -1.4426950408889634f   // -log2(e)
#define N2LOG2E -2.8853900817779268f   // -2*log2(e)

__device__ __forceinline__ float fast_rcp(float x) { return __builtin_amdgcn_rcpf(x); }
__device__ __forceinline__ float exp2f_hw(float x) { return __builtin_amdgcn_exp2f(x); }
__device__ __forceinline__ unsigned short f16bits(float f) {
    _Float16 h = (_Float16)f;                 // v_cvt_f16_f32 (RNE)
    return __builtin_bit_cast(unsigned short, h);
}
__device__ __forceinline__ float f16tof(unsigned short b) {
    return (float)__builtin_bit_cast(_Float16, b);
}
// merge: per 16-lane row, lanes 0..7 keep a (L1 acc), lanes 8..15 take
// lane-8's b (L2 acc). row_shr:8 = 0x118; bank_mask 0xC enables banks 2,3.
__device__ __forceinline__ float dpp_merge(float a, float b) {
    return __int_as_float(__builtin_amdgcn_update_dpp(
        __float_as_int(a), __float_as_int(b), 0x118, 0xF, 0xC, false));
}

// frag-ready blocked layout: idx = (k>>3)*128 + n*8 + (k&7), k<128, n<16
__device__ __forceinline__ int vidx(int k, int n) {
    return ((k >> 3) << 7) + n * 8 + (k & 7);
}

__global__ __launch_bounds__(NT) void lstm_kernel(
    const float* __restrict__ x,
    const float* __restrict__ W_ih1, const float* __restrict__ W_hh1,
    const float* __restrict__ b_ih1, const float* __restrict__ b_hh1,
    const float* __restrict__ W_ih2, const float* __restrict__ W_hh2,
    const float* __restrict__ b_ih2, const float* __restrict__ b_hh2,
    const float* __restrict__ W_lin, const float* __restrict__ b_lin,
    float* __restrict__ out)
{
    __shared__ float xs[TT * NB];                                     // 32 KB
    __shared__ __attribute__((aligned(16))) unsigned short v[2][VSZ]; // 8.25 KB

    const int tid  = threadIdx.x;
    const int w    = tid >> 6;       // wave 0..12
    const int L    = tid & 63;
    const int quad = L >> 4;
    const int n15  = L & 15;
    const int b0g  = blockIdx.x * NB;

    const int  m     = w;                // tile per wave
    const int  u     = m * 4 + quad;     // unit this lane updates
    const bool low   = (n15 < NB);       // low half: L1 / B loads
    const bool updOK = (u < HH);
    const bool ldB   = low;
    // wave 12's quad-2 lanes (u=50, update-invalid) stage x(t+1)
    const bool xw    = (w == 12) && (L >= 32) && (L < 32 + NB);
    const int  xb    = L - 32;
    // h slot: low -> h1 (k=1+u), high -> h2 (k=51+u); invalid u -> dump tail
    const int hslot = updOK ? (low ? vidx(1 + u, n15) : vidx(51 + u, n15 - NB))
                            : (2048 + L);

    for (int i = tid; i < 2 * VSZ; i += NT) ((unsigned short*)v)[i] = 0;
    for (int i = tid; i < NB * TT; i += NT) {   // stage x transposed xs[t][b]
        int b = i >> 10, t = i & 1023;
        xs[t * NB + b] = x[(size_t)b0g * TT + i];
    }

    // ---- per-wave A-frags: fp16, pre-scaled by -log2e (g rows: -2log2e) ----
    f16x8 a1[2], a2[4];
    f32x4 bias1 = {0.f, 0.f, 0.f, 0.f}, bias2 = {0.f, 0.f, 0.f, 0.f};
    float c = 0.f;    // low lanes: c1, high lanes: c2

    {
        const int arow = m * 16 + n15;
        const bool av = (arow < 200);
        const int r = av ? ((arow & 3) * 50 + (arow >> 2)) : 0;  // type*50+unit
        const float sc = ((arow & 3) == 2) ? N2LOG2E : NLOG2E;
        #pragma unroll
        for (int kt = 0; kt < 2; ++kt) {    // L1 A: k=0 -> W_ih1, k in [1,50] -> W_hh1
            ushort8 th;
            #pragma unroll
            for (int j = 0; j < 8; ++j) {
                int k = kt * 32 + quad * 8 + j;
                float wv = 0.f;
                if (av) { if (k == 0) wv = W_ih1[r]; else if (k <= 50) wv = W_hh1[r * 50 + k - 1]; }
                th[j] = f16bits(wv * sc);
            }
            a1[kt] = __builtin_bit_cast(f16x8, th);
        }
        #pragma unroll
        for (int kt = 0; kt < 4; ++kt) {    // L2 A: k 1..50 -> W_ih2, 51..100 -> W_hh2
            ushort8 th;
            #pragma unroll
            for (int j = 0; j < 8; ++j) {
                int k = kt * 32 + quad * 8 + j;
                float wv = 0.f;
                if (av) {
                    if (k >= 1 && k <= 50) wv = W_ih2[r * 50 + k - 1];
                    else if (k >= 51 && k <= 100) wv = W_hh2[r * 50 + k - 51];
                }
                th[j] = f16bits(wv * sc);
            }
            a2[kt] = __builtin_bit_cast(f16x8, th);
        }
        #pragma unroll
        for (int reg = 0; reg < 4; ++reg) {
            int crow = m * 16 + quad * 4 + reg;
            if (crow < 200) {
                int rr = (crow & 3) * 50 + (crow >> 2);
                float s2 = ((crow & 3) == 2) ? N2LOG2E : NLOG2E;
                bias1[reg] = s2 * (b_ih1[rr] + b_hh1[rr]);
                bias2[reg] = s2 * (b_ih2[rr] + b_hh2[rr]);
            }
        }
    }

    __syncthreads();
    if (tid < NB) v[0][vidx(0, tid)] = f16bits(xs[0 * NB + tid]);  // x(0)
    __syncthreads();

    f16x8 bfr[4];
    #pragma unroll
    for (int kt = 0; kt < 4; ++kt)
        bfr[kt] = __builtin_bit_cast(f16x8, ushort8{0,0,0,0,0,0,0,0});

    // one step: iter t = L1 gates(t) + L2 gates(t-1); read vr, write vw.
    // Accumulators hold -g*log2e (g rows: -2g*log2e) -> raw v_exp gives e^-g.
    auto body = [&](int t, const unsigned short* vr, unsigned short* vw,
                    bool doL1, bool doL2, bool masked) {
        if (ldB) {
            #pragma unroll
            for (int kt = 0; kt < 4; ++kt)
                bfr[kt] = ((const f16x8*)vr)[kt * 64 + L];
        }
        f32x4 aM1 = bias1, aM2 = bias2;
        if (doL1) {
            #pragma unroll
            for (int kt = 0; kt < 2; ++kt)
                aM1 = __builtin_amdgcn_mfma_f32_16x16x32_f16(a1[kt], bfr[kt], aM1, 0, 0, 0);
        }
        if (doL2) {
            #pragma unroll
            for (int kt = 0; kt < 4; ++kt)
                aM2 = __builtin_amdgcn_mfma_f32_16x16x32_f16(a2[kt], bfr[kt], aM2, 0, 0, 0);
        }
        // merge: low 8 of each 16-row keep L1 acc, high 8 take partner L2 acc
        f32x4 g;
        #pragma unroll
        for (int r = 0; r < 4; ++r) g[r] = dpp_merge(aM1[r], aM2[r]);

        // cell update: g = (-i, -f, -2gg, -o)*log2e; single-rcp cn
        if (!masked || (updOK && low)) {
            float ei = exp2f_hw(g[0]);           // e^-i
            float ef = exp2f_hw(g[1]);           // e^-f
            float eg = exp2f_hw(g[2]);           // e^-2gg
            float eo = exp2f_hw(g[3]);           // e^-o
            float p  = (1.0f + ei) * (1.0f + eg);
            float q  = (1.0f - eg) * (1.0f + ef);
            float cn = fmaf(c, p, q) * fast_rcp(p * (1.0f + ef));
            c = cn;
            float ecn = exp2f_hw(cn * N2LOG2E);  // e^-2c
            float h = (1.0f - ecn) * fast_rcp((1.0f + eo) * (1.0f + ecn));
            vw[hslot] = f16bits(h);
        }
        if (xw && t + 1 < TT) vw[vidx(0, xb)] = f16bits(xs[(t + 1) * NB + xb]);
        __syncthreads();
    };

    // peel t=0 (no L2 yet: masked update protects high-half c), steady, tail.
    body(0, v[0], v[1], true, false, true);
    body(1, v[1], v[0], true, true, false);
    for (int t = 2; t < TT; t += 2) {
        body(t,     v[0], v[1], true, true, false);
        body(t + 1, v[1], v[0], true, true, false);
    }
    // tail: L2 gates(TT-1) only; low-half h1/c1 writes are dead
    body(TT, v[0], v[1], false, true, false);

    // epilogue: h2(T-1) sits in buf1 slots 51..100
    if (tid < NB) {
        float s = b_lin[0];
        #pragma unroll
        for (int uu = 0; uu < HH; ++uu)
            s += W_lin[uu] * f16tof(v[1][vidx(51 + uu, tid)]);
        out[b0g + tid] = s;
    }
}

extern "C" void kernel_launch(void* const* d_in, const int* in_sizes, int n_in,
                              void* d_out, int out_size, void* d_ws, size_t ws_size,
                              hipStream_t stream) {
    const float* x     = (const float*)d_in[0];
    const float* W_ih1 = (const float*)d_in[1];
    const float* W_hh1 = (const float*)d_in[2];
    const float* b_ih1 = (const float*)d_in[3];
    const float* b_hh1 = (const float*)d_in[4];
    const float* W_ih2 = (const float*)d_in[5];
    const float* W_hh2 = (const float*)d_in[6];
    const float* b_ih2 = (const float*)d_in[7];
    const float* b_hh2 = (const float*)d_in[8];
    const float* W_lin = (const float*)d_in[9];
    const float* b_lin = (const float*)d_in[10];
    float* out = (float*)d_out;

    const int Btot = in_sizes[0] / TT;   // 2048
    const int nblocks = Btot / NB;       // 256 -> 1 block/CU

    lstm_kernel<<<nblocks, NT, 0, stream>>>(
        x, W_ih1, W_hh1, b_ih1, b_hh1, W_ih2, W_hh2, b_ih2, b_hh2,
        W_lin, b_lin, out);
}